// Round 3
// baseline (134.155 us; speedup 1.0000x reference)
//
#include <hip/hip_runtime.h>

// ---------------------------------------------------------------------------
// metaLinear: y[t,o] = sum_j x2[t,j] * ( x1[t,:]@W[j*64+o,:] + bvec[j*64+o] )
//   T=16384, IN1=256, IN2=64 (j), OUT=64 (o).
// Round 3: LDS double-buffered W tiles via global_load_lds (zero VGPR
// prefetch, one fetch per WG per j, one barrier per j). Bias handled as a
// separate 64x64 matmul folded into 4 epilogue MFMAs (y += x2 @ Bmat,
// Bmat[j][o] = bvec[j*64+o]), so the j-loop is exactly 16 MFMAs.
// Per-j ds_reads are issued BEFORE the DMA batch so no vmcnt wait lands
// between them; only the end-of-j barrier drains.
// ---------------------------------------------------------------------------

#define FRAG_SHORTS 512                 // 64 lanes * 8 bf16
#define TILE_SHORTS (2 * 16 * FRAG_SHORTS)   // 16384 shorts = 32768 B per j
#define TILE_BYTES  32768
#define NTILES 65                       // 64 real + 1 dummy prefetch target

typedef __bf16 bf16x8 __attribute__((ext_vector_type(8)));
typedef float  f32x16 __attribute__((ext_vector_type(16)));

static __device__ __forceinline__ unsigned short f2bf(float f) {
  union { float f; unsigned u; } v; v.f = f;
  unsigned r = v.u + 0x7FFFu + ((v.u >> 16) & 1u);   // RNE
  return (unsigned short)(r >> 16);
}

// Wf[((j*2+oh)*16 + ks)*512 + lane*8 + e] =
//     bf16( W[row = 64j+32oh+(lane&31)][col = 16ks + 8*(lane>>5) + e] )
// One wave per (j,oh,ks): reads one 64B line per row (lg0/lg1 halves),
// writes a contiguous 1 KB fragment (perfectly coalesced).
__global__ void prep_w(const float* __restrict__ W, unsigned short* __restrict__ Wf) {
  int wv   = threadIdx.x >> 6;
  int lane = threadIdx.x & 63;
  int l31  = lane & 31;
  int lg   = lane >> 5;
  int task = blockIdx.x * 4 + wv;       // 0..2047
  int ks   = task & 15;
  int joh  = task >> 4;                 // j*2+oh, 0..127
  int r    = 32 * joh + l31;            // = 64j + 32oh + l31
  int col  = ks * 16 + lg * 8;

  const float4* src = (const float4*)(W + (size_t)r * 256 + col);
  float4 a = src[0], b = src[1];
  ushort4 u0, u1;
  u0.x = f2bf(a.x); u0.y = f2bf(a.y); u0.z = f2bf(a.z); u0.w = f2bf(a.w);
  u1.x = f2bf(b.x); u1.y = f2bf(b.y); u1.z = f2bf(b.z); u1.w = f2bf(b.w);
  size_t fb = ((size_t)joh * 16 + ks) * FRAG_SHORTS;
  *(ushort4*)&Wf[fb + lane * 8 + 0] = u0;
  *(ushort4*)&Wf[fb + lane * 8 + 4] = u1;
}

// 256 WGs x 256 threads (4 waves). WG g owns tokens [g*64, g*64+64).
// Wave w: th = w&1 (token 32-subtile), oh = w>>1 (output 32-subtile).
__global__ __launch_bounds__(256, 1)
void meta_main(const float* __restrict__ x1, const float* __restrict__ x2,
               const float* __restrict__ bvec,
               const unsigned short* __restrict__ Wf, float* __restrict__ out) {
  __shared__ unsigned short sW[2 * TILE_SHORTS];   // 65536 B: dbuf; also used
                                                   // for x1 staging + bvec cvt

  const int tid  = threadIdx.x;
  const int lane = tid & 63;
  const int wv   = tid >> 6;
  const int th   = wv & 1;
  const int oh   = wv >> 1;
  const int l31  = lane & 31;
  const int lg   = lane >> 5;
  const int tt   = 32 * th + l31;
  const long tile0 = (long)blockIdx.x * 64;

  // ---- prologue: stage x1 tile fp32 -> bf16 into sW (row stride 264) ----
  {
    const float4* src = (const float4*)(x1 + tile0 * 256);
    #pragma unroll
    for (int it = 0; it < 16; ++it) {
      int fi4 = it * 256 + tid;
      float4 v = src[fi4];
      int token = fi4 >> 6;
      int col   = (fi4 & 63) * 4;
      ushort4 b;
      b.x = f2bf(v.x); b.y = f2bf(v.y); b.z = f2bf(v.z); b.w = f2bf(v.w);
      *(ushort4*)&sW[token * 264 + col] = b;
    }
  }
  __syncthreads();

  // x1 B-frags, register-resident for the whole j-loop
  bf16x8 bfrag[16];
  {
    const unsigned short* base = &sW[tt * 264 + lg * 8];
    #pragma unroll
    for (int ks = 0; ks < 16; ++ks)
      bfrag[ks] = *(const bf16x8*)(base + ks * 16);
  }
  __syncthreads();                       // all bfrag reads done; sW reusable

  // prefetch tile 0 into buf 0
  {
    const char* g = (const char*)Wf;
    char* l = (char*)sW;
    #pragma unroll
    for (int c = 0; c < 8; ++c)
      __builtin_amdgcn_global_load_lds(
          (const __attribute__((address_space(1))) unsigned int*)(g + tid * 16 + c * 4096),
          (__attribute__((address_space(3))) unsigned int*)(l + tid * 16 + c * 4096),
          16, 0, 0);
  }
  __syncthreads();                       // tile 0 resident

  f32x16 yacc;
  #pragma unroll
  for (int r = 0; r < 16; ++r) yacc[r] = 0.0f;

  const float4* x2g = (const float4*)(x2 + (tile0 + tt) * 64);

  auto step = [&](int j, int b, float x2s) {
    // 1) consume: all 16 A-frags first (no DMA->ds_read hazard in this j)
    bf16x8 af[16];
    const unsigned short* abase = &sW[b * TILE_SHORTS + oh * 8192 + lane * 8];
    #pragma unroll
    for (int ks = 0; ks < 16; ++ks)
      af[ks] = *(const bf16x8*)(abase + ks * FRAG_SHORTS);
    // 2) prefetch tile j+1 into the other buffer (j=63 -> dummy tile 64)
    {
      const char* g = (const char*)Wf + (size_t)(j + 1) * TILE_BYTES;
      char* l = ((char*)sW) + (b ^ 1) * TILE_BYTES;
      #pragma unroll
      for (int c = 0; c < 8; ++c)
        __builtin_amdgcn_global_load_lds(
            (const __attribute__((address_space(1))) unsigned int*)(g + tid * 16 + c * 4096),
            (__attribute__((address_space(3))) unsigned int*)(l + tid * 16 + c * 4096),
            16, 0, 0);
    }
    // 3) compute: 16 MFMAs in two chains, then fp32 stage-2
    f32x16 wlo, whi;
    #pragma unroll
    for (int r = 0; r < 16; ++r) { wlo[r] = 0.0f; whi[r] = 0.0f; }
    #pragma unroll
    for (int ks = 0; ks < 8; ++ks)
      wlo = __builtin_amdgcn_mfma_f32_32x32x16_bf16(af[ks], bfrag[ks], wlo, 0, 0, 0);
    #pragma unroll
    for (int ks = 8; ks < 16; ++ks)
      whi = __builtin_amdgcn_mfma_f32_32x32x16_bf16(af[ks], bfrag[ks], whi, 0, 0, 0);
    #pragma unroll
    for (int r = 0; r < 16; ++r)
      yacc[r] += x2s * (wlo[r] + whi[r]);
    __syncthreads();                     // drains prefetch; buffers swap safe
  };

  for (int g = 0; g < 16; ++g) {
    float4 q = x2g[g];                   // x2[tt][4g..4g+3], L1/L2-hot
    step(4 * g + 0, 0, q.x);
    step(4 * g + 1, 1, q.y);
    step(4 * g + 2, 0, q.z);
    step(4 * g + 3, 1, q.w);
  }

  // ---- epilogue A: bias term  y[t,o] += sum_j x2[t,j]*bvec[j*64+o] ----
  // Convert bvec to bf16 in sW (loop is done; last barrier already passed).
  {
    const float4* bsrc = (const float4*)bvec;         // 1024 float4
    #pragma unroll
    for (int c = 0; c < 4; ++c) {
      float4 v = bsrc[c * 256 + tid];
      ushort4 u;
      u.x = f2bf(v.x); u.y = f2bf(v.y); u.z = f2bf(v.z); u.w = f2bf(v.w);
      *(ushort4*)&sW[(c * 256 + tid) * 4] = u;
    }
  }
  __syncthreads();
  {
    const __bf16* bb = (const __bf16*)sW;
    #pragma unroll
    for (int k = 0; k < 4; ++k) {
      bf16x8 Af, Bf;
      #pragma unroll
      for (int e = 0; e < 8; ++e)        // A[m=o][k'=j'] = bvec[j'*64+o]
        Af[e] = bb[(16 * k + 8 * lg + e) * 64 + 32 * oh + l31];
      const float* xr = x2 + (size_t)(tile0 + tt) * 64 + 16 * k + 8 * lg;
      float4 p0 = *(const float4*)xr;
      float4 p1 = *(const float4*)(xr + 4);
      Bf[0] = (__bf16)p0.x; Bf[1] = (__bf16)p0.y; Bf[2] = (__bf16)p0.z; Bf[3] = (__bf16)p0.w;
      Bf[4] = (__bf16)p1.x; Bf[5] = (__bf16)p1.y; Bf[6] = (__bf16)p1.z; Bf[7] = (__bf16)p1.w;
      yacc = __builtin_amdgcn_mfma_f32_32x32x16_bf16(Af, Bf, yacc, 0, 0, 0);
    }
  }

  // ---- epilogue B: store. D row = (r&3)+8*(r>>2)+4*lg, col = t = l31 ----
  float* yout = out + (tile0 + tt) * 64 + oh * 32;
  #pragma unroll
  for (int q4 = 0; q4 < 4; ++q4) {
    float4 v;
    v.x = yacc[4 * q4 + 0]; v.y = yacc[4 * q4 + 1];
    v.z = yacc[4 * q4 + 2]; v.w = yacc[4 * q4 + 3];
    *(float4*)&yout[q4 * 8 + 4 * lg] = v;
  }
}

extern "C" void kernel_launch(void* const* d_in, const int* in_sizes, int n_in,
                              void* d_out, int out_size, void* d_ws, size_t ws_size,
                              hipStream_t stream) {
  const float* x1 = (const float*)d_in[0];   // (4,4096,256) f32
  const float* x2 = (const float*)d_in[1];   // (4,4096,64)  f32
  const float* W  = (const float*)d_in[2];   // (4096,256)   f32
  const float* bv = (const float*)d_in[3];   // (4096,)      f32
  float* y = (float*)d_out;                  // (4,4096,64)  f32
  unsigned short* Wf = (unsigned short*)d_ws;  // 65*32768 = 2,129,920 B

  prep_w<<<512, 256, 0, stream>>>(W, Wf);
  meta_main<<<256, 256, 0, stream>>>(x1, x2, bv, Wf, y);
}